// Round 3
// baseline (360.659 us; speedup 1.0000x reference)
//
#include <hip/hip_runtime.h>

// 6-point periodic stencil + DGPE ODE RHS on a 192^3 lattice.
// v3: float4-vectorized + forced memory-level parallelism.
//     v2 post-mortem: compiler chose 32 VGPRs and serialized the 21 loads
//     into ~4 dependent batches -> latency-bound at 2.15 TB/s.
//     Fix: __launch_bounds__(256,4) lifts the VGPR cap to 128, and a
//     sched_barrier(0) after the load block keeps all 21 loads in flight
//     before the first s_waitcnt. y-field (HBM-latency) loads issue first,
//     LLC-resident param loads last.
// Neighbor indices computed arithmetically (index arrays unused).

#define LDIM 192
#define LSQ  (LDIM * LDIM)          // 36864
#define NTOT (LDIM * LDIM * LDIM)   // 7077888
#define NQ   (NTOT / 4)             // 1769472 float4 cells
#define LSQ4 (LSQ / 4)              // 9216  (plane stride in float4)
#define LD4  (LDIM / 4)             // 48    (row stride in float4)

typedef float floatx4 __attribute__((ext_vector_type(4)));

__global__ __launch_bounds__(256, 4) void dgpe_kernel(
    const float* __restrict__ y,
    const float* __restrict__ Jarr,
    const float* __restrict__ aniso,
    const float* __restrict__ gam,
    const float* __restrict__ hdx,
    const float* __restrict__ hdy,
    const float* __restrict__ beta,
    const float* __restrict__ edis,
    float* __restrict__ out)
{
    const int q = blockIdx.x * blockDim.x + threadIdx.x;

    // decompose q (float4 index) = a*9216 + b*48 + cq
    const unsigned uq  = (unsigned)q;
    const unsigned a   = uq / LSQ4;
    const unsigned rem = uq - a * LSQ4;
    const unsigned b   = rem / LD4;
    const unsigned cq  = rem - b * LD4;

    // periodic neighbors, float4 index space for x/y dirs
    const int xm4 = (a == 0)        ? q + (LDIM - 1) * LSQ4 : q - LSQ4;
    const int xp4 = (a == LDIM - 1) ? q - (LDIM - 1) * LSQ4 : q + LSQ4;
    const int ym4 = (b == 0)        ? q + (LDIM - 1) * LD4  : q - LD4;
    const int yp4 = (b == LDIM - 1) ? q - (LDIM - 1) * LD4  : q + LD4;

    // z-direction edge scalars (float index space)
    const int i   = q * 4;
    const int zmi = (cq == 0)       ? i + (LDIM - 1) : i - 1;  // elem 0's z-minus
    const int zpi = (cq == LD4 - 1) ? i - (LDIM - 4) : i + 4;  // elem 3's z-plus

    const floatx4* __restrict__ x4 = (const floatx4*)y;
    const floatx4* __restrict__ p4 = (const floatx4*)(y + NTOT);
    const float*   __restrict__ x  = y;
    const float*   __restrict__ p  = y + NTOT;

    // ---- load block: issue everything, longest-latency first ----
    const floatx4 xc  = x4[q];
    const floatx4 xxm = x4[xm4];
    const floatx4 xxp = x4[xp4];
    const floatx4 xym = x4[ym4];
    const floatx4 xyp = x4[yp4];
    const float   xzm = x[zmi];
    const float   xzp = x[zpi];

    const floatx4 pc  = p4[q];
    const floatx4 pxm = p4[xm4];
    const floatx4 pxp = p4[xp4];
    const floatx4 pym = p4[ym4];
    const floatx4 pyp = p4[yp4];
    const float   pzm = p[zmi];
    const float   pzp = p[zpi];

    const floatx4 Jv  = ((const floatx4*)Jarr )[q];
    const floatx4 anv = ((const floatx4*)aniso)[q];
    const floatx4 gv  = ((const floatx4*)gam  )[q];
    const floatx4 edv = ((const floatx4*)edis )[q];
    const floatx4 btv = ((const floatx4*)beta )[q];
    const floatx4 hxv = ((const floatx4*)hdx  )[q];
    const floatx4 hyv = ((const floatx4*)hdy  )[q];

    // keep all loads issued before any consumption is scheduled
    __builtin_amdgcn_sched_barrier(0);

    // z neighbors: interior ones come from the center float4 (register shuffle)
    const floatx4 xzmv = {xzm,   xc.x,  xc.y,  xc.z};
    const floatx4 xzpv = {xc.y,  xc.z,  xc.w,  xzp};
    const floatx4 pzmv = {pzm,   pc.x,  pc.y,  pc.z};
    const floatx4 pzpv = {pc.y,  pc.z,  pc.w,  pzp};

    floatx4 odx, odp;
#pragma unroll
    for (int e = 0; e < 4; ++e) {
        const float Ji = Jv[e];
        const float an = anv[e];
        const float xi = xc[e];
        const float pi = pc[e];

        const float xL = Ji * (xxm[e] + xxp[e] + xym[e] + xyp[e]
                               + an * (xzmv[e] + xzpv[e]));
        const float yL = Ji * (pxm[e] + pxp[e] + pym[e] + pyp[e]
                               + an * (pzmv[e] + pzpv[e]));

        const float g  = gv[e];
        const float ed = edv[e];
        const float bt = btv[e];

        const float r2    = xi * xi + pi * pi;
        const float cross = xL * pi - yL * xi;

        odx[e] =  g * pi * cross + ed * pi - yL + hyv[e] + bt * r2 * pi;
        odp[e] = -g * xi * cross - ed * xi + xL - hxv[e] - bt * r2 * xi;
    }

    floatx4* __restrict__ o4 = (floatx4*)out;
    __builtin_nontemporal_store(odx, &o4[q]);
    __builtin_nontemporal_store(odp, &o4[q + NQ]);
}

extern "C" void kernel_launch(void* const* d_in, const int* in_sizes, int n_in,
                              void* d_out, int out_size, void* d_ws, size_t ws_size,
                              hipStream_t stream) {
    // d_in: 0=t, 1=y, 2=J, 3=anisotropy, 4=gamma, 5=h_dis_x, 6=h_dis_y,
    //       7=beta, 8=e_disorder, 9..14=neighbor index arrays (unused)
    const float* y_    = (const float*)d_in[1];
    const float* Jarr  = (const float*)d_in[2];
    const float* aniso = (const float*)d_in[3];
    const float* gam   = (const float*)d_in[4];
    const float* hdx   = (const float*)d_in[5];
    const float* hdy   = (const float*)d_in[6];
    const float* beta  = (const float*)d_in[7];
    const float* edis  = (const float*)d_in[8];
    float* out = (float*)d_out;

    const int threads = 256;
    const int blocks  = NQ / threads;  // 6912, exact
    dgpe_kernel<<<blocks, threads, 0, stream>>>(y_, Jarr, aniso, gam, hdx, hdy,
                                                beta, edis, out);
}

// Round 4
// 353.723 us; speedup vs baseline: 1.0196x; 1.0196x over previous
//
#include <hip/hip_runtime.h>

// 6-point periodic stencil + DGPE ODE RHS on a 192^3 lattice.
// v4: scalar one-element-per-thread (max TLP, like v1) + forced full MLP.
//     v2/v3 post-mortem: compiler serializes loads into small VGPR-limited
//     batches with waitcnt-to-zero between them; sched_barrier(0) was
//     defeated at IR level (loads sunk to uses before the machine
//     scheduler ran). Fix: an empty `asm volatile` consuming every loaded
//     value as a "v" operand — forces all 21 values simultaneously live,
//     so all 21 loads issue before a single s_waitcnt. y-field loads
//     (HBM latency) issue first, LLC-resident param loads last.
// Neighbor indices computed arithmetically (index arrays unused).

#define LDIM 192
#define LSQ  (LDIM * LDIM)          // 36864
#define NTOT (LDIM * LDIM * LDIM)   // 7077888 = 256 * 27648

__global__ __launch_bounds__(256) void dgpe_kernel(
    const float* __restrict__ y,
    const float* __restrict__ Jarr,
    const float* __restrict__ aniso,
    const float* __restrict__ gam,
    const float* __restrict__ hdx,
    const float* __restrict__ hdy,
    const float* __restrict__ beta,
    const float* __restrict__ edis,
    float* __restrict__ out)
{
    const int i = blockIdx.x * blockDim.x + threadIdx.x;

    const float* __restrict__ x = y;
    const float* __restrict__ p = y + NTOT;

    // decompose i = a*L^2 + b*L + c (compiler emits magic-multiply for /192)
    const unsigned ui  = (unsigned)i;
    const unsigned a   = ui / LSQ;
    const unsigned rem = ui - a * LSQ;
    const unsigned b   = rem / LDIM;
    const unsigned c   = rem - b * LDIM;

    // periodic neighbors (flat offsets with wrap)
    const int xm = (a == 0)        ? i + (LDIM - 1) * LSQ  : i - LSQ;
    const int xp = (a == LDIM - 1) ? i - (LDIM - 1) * LSQ  : i + LSQ;
    const int ym = (b == 0)        ? i + (LDIM - 1) * LDIM : i - LDIM;
    const int yp = (b == LDIM - 1) ? i - (LDIM - 1) * LDIM : i + LDIM;
    const int zm = (c == 0)        ? i + (LDIM - 1)        : i - 1;
    const int zp = (c == LDIM - 1) ? i - (LDIM - 1)        : i + 1;

    // ---- issue ALL loads; longest-latency (y fields) first ----
    const float xi  = x[i];
    const float xxm = x[xm];
    const float xxp = x[xp];
    const float xym = x[ym];
    const float xyp = x[yp];
    const float xzm = x[zm];
    const float xzp = x[zp];

    const float pi  = p[i];
    const float pxm = p[xm];
    const float pxp = p[xp];
    const float pym = p[ym];
    const float pyp = p[yp];
    const float pzm = p[zm];
    const float pzp = p[zp];

    const float Ji = Jarr[i];
    const float an = aniso[i];
    const float g  = gam[i];
    const float ed = edis[i];
    const float bt = beta[i];
    const float hx = hdx[i];
    const float hy = hdy[i];

    // Liveness clamp: force every loaded value to be simultaneously resident
    // in VGPRs here -> compiler must issue all 21 loads before one waitcnt.
    asm volatile("" ::
        "v"(xi),  "v"(xxm), "v"(xxp), "v"(xym), "v"(xyp), "v"(xzm), "v"(xzp),
        "v"(pi),  "v"(pxm), "v"(pxp), "v"(pym), "v"(pyp), "v"(pzm), "v"(pzp),
        "v"(Ji),  "v"(an),  "v"(g),   "v"(ed),  "v"(bt),  "v"(hx),  "v"(hy));

    const float xL = Ji * (xxm + xxp + xym + xyp + an * (xzm + xzp));
    const float yL = Ji * (pxm + pxp + pym + pyp + an * (pzm + pzp));

    const float r2    = xi * xi + pi * pi;
    const float cross = xL * pi - yL * xi;

    const float dx =  g * pi * cross + ed * pi - yL + hy + bt * r2 * pi;
    const float dp = -g * xi * cross - ed * xi + xL - hx - bt * r2 * xi;

    __builtin_nontemporal_store(dx, &out[i]);
    __builtin_nontemporal_store(dp, &out[i + NTOT]);
}

extern "C" void kernel_launch(void* const* d_in, const int* in_sizes, int n_in,
                              void* d_out, int out_size, void* d_ws, size_t ws_size,
                              hipStream_t stream) {
    // d_in: 0=t, 1=y, 2=J, 3=anisotropy, 4=gamma, 5=h_dis_x, 6=h_dis_y,
    //       7=beta, 8=e_disorder, 9..14=neighbor index arrays (unused)
    const float* y_    = (const float*)d_in[1];
    const float* Jarr  = (const float*)d_in[2];
    const float* aniso = (const float*)d_in[3];
    const float* gam   = (const float*)d_in[4];
    const float* hdx   = (const float*)d_in[5];
    const float* hdy   = (const float*)d_in[6];
    const float* beta  = (const float*)d_in[7];
    const float* edis  = (const float*)d_in[8];
    float* out = (float*)d_out;

    const int threads = 256;
    const int blocks  = NTOT / threads;  // 27648, exact
    dgpe_kernel<<<blocks, threads, 0, stream>>>(y_, Jarr, aniso, gam, hdx, hdy,
                                                beta, edis, out);
}